// Round 14
// baseline (247.951 us; speedup 1.0000x reference)
//
#include <hip/hip_runtime.h>

// ---------------------------------------------------------------------------
// Fused GQA attention block for MI355X (gfx950), bf16 MFMA pipeline.
// B=1, S=4096, H=2048, NH=16, NKV=4, HD=128, GROUPS=4, causal mask hardcoded.
// Round 14: attention frozen (r8/r12 body, 130.5us). GEMM upgraded to
// double-buffered LDS (2x32KB, still 2 blocks/CU) with counted vmcnt(8) --
// removes the per-K-step vmcnt(0)+syncthreads full drain (the m97-class ~20%
// structural stall). STAGE(kt+2) issued right after the read-side barrier,
// exactly the pipeline already proven in the attn kernel.
// ---------------------------------------------------------------------------

typedef __bf16 bf16;
typedef float f32x4 __attribute__((ext_vector_type(4)));
typedef float f32x16 __attribute__((ext_vector_type(16)));
typedef bf16 bf16x4 __attribute__((ext_vector_type(4)));
typedef bf16 bf16x8 __attribute__((ext_vector_type(8)));
typedef unsigned u32x4 __attribute__((ext_vector_type(4)));

#define MFMA16(A, B, C) __builtin_amdgcn_mfma_f32_16x16x32_bf16((A), (B), (C), 0, 0, 0)
#define MFMA32(A, B, C) __builtin_amdgcn_mfma_f32_32x32x16_bf16((A), (B), (C), 0, 0, 0)

__device__ __forceinline__ void async16(const bf16* g, bf16* l) {
  __builtin_amdgcn_global_load_lds(
      (const __attribute__((address_space(1))) unsigned int*)g,
      (__attribute__((address_space(3))) unsigned int*)l, 16, 0, 0);
}

__device__ __forceinline__ float exp2v(float x) {
  float r; asm("v_exp_f32 %0, %1" : "=v"(r) : "v"(x)); return r;
}
__device__ __forceinline__ unsigned cvtpk(float a, float b) {  // lo=a, hi=b
  unsigned r; asm("v_cvt_pk_bf16_f32 %0, %1, %2" : "=v"(r) : "v"(a), "v"(b)); return r;
}
// v_permlane32_swap_b32: a' = [a_lo|b_lo], b' = [a_hi|b_hi].
// ONLY safe when a and b are distinct SSA values (else RA may coalesce regs).
#define PLSWAP(a, b) asm("v_permlane32_swap_b32 %0, %1" : "+v"(a), "+v"(b))

// B-fragment builder: dwords {a0', a1', c0', c1'} after half-swaps
__device__ __forceinline__ bf16x8 mkfrag(unsigned a0, unsigned a1,
                                         unsigned c0, unsigned c1) {
  PLSWAP(a0, c0);
  PLSWAP(a1, c1);
  u32x4 t = {a0, a1, c0, c1};
  return __builtin_bit_cast(bf16x8, t);
}

// ---------------------------------------------------------------------------
// f32 -> bf16 elementwise cast
// ---------------------------------------------------------------------------
__global__ void cast_bf16_kernel(const float* __restrict__ in,
                                 bf16* __restrict__ out, int n4) {
  int i = blockIdx.x * blockDim.x + threadIdx.x;
  int stride = gridDim.x * blockDim.x;
  for (; i < n4; i += stride) {
    float4 v = ((const float4*)in)[i];
    bf16x4 o = {(bf16)v.x, (bf16)v.y, (bf16)v.z, (bf16)v.w};
    ((bf16x4*)out)[i] = o;
  }
}

// ---------------------------------------------------------------------------
// Transpose + cast: src f32 [2048][srcCols] -> dst bf16 [srcCols][2048], *scale
// ---------------------------------------------------------------------------
__global__ void transpose_cast_kernel(const float* __restrict__ src, int srcCols,
                                      bf16* __restrict__ dst, float scale) {
  __shared__ float t[64][65];
  const int kt = blockIdx.y * 64;
  const int nt = blockIdx.x * 64;
  const int r0 = threadIdx.x >> 4;
  const int c0 = (threadIdx.x & 15) * 4;
#pragma unroll
  for (int i = 0; i < 4; ++i) {
    int r = r0 + i * 16;
    float4 v = *(const float4*)(src + (kt + r) * srcCols + nt + c0);
    t[r][c0 + 0] = v.x; t[r][c0 + 1] = v.y; t[r][c0 + 2] = v.z; t[r][c0 + 3] = v.w;
  }
  __syncthreads();
#pragma unroll
  for (int i = 0; i < 4; ++i) {
    int r = r0 + i * 16;
    bf16x4 b = {(bf16)(t[c0 + 0][r] * scale), (bf16)(t[c0 + 1][r] * scale),
                (bf16)(t[c0 + 2][r] * scale), (bf16)(t[c0 + 3][r] * scale)};
    *(bf16x4*)(dst + (nt + r) * 2048 + kt + c0) = b;
  }
}

// ---------------------------------------------------------------------------
// Merged Wq/Wk/Wv transpose+cast into WT (one launch instead of three).
// blockIdx.x: 0..31 -> Wq (32 col-tiles), 32..39 -> Wk, 40..47 -> Wv.
// ---------------------------------------------------------------------------
__global__ void transpose_qkv_kernel(const float* __restrict__ Wq,
                                     const float* __restrict__ Wk,
                                     const float* __restrict__ Wv,
                                     bf16* __restrict__ WT) {
  __shared__ float t[64][65];
  const int bx = blockIdx.x;
  const float* src;
  int srcCols, ntl, dstRow;
  float scale;
  if (bx < 32) {
    src = Wq; srcCols = 2048; ntl = bx; dstRow = 0;
    scale = 0.08838834764831845f * 1.4426950408889634f;  // 1/sqrt(128) * log2e
  } else if (bx < 40) {
    src = Wk; srcCols = 512; ntl = bx - 32; dstRow = 2048; scale = 1.0f;
  } else {
    src = Wv; srcCols = 512; ntl = bx - 40; dstRow = 2560; scale = 1.0f;
  }
  const int kt = blockIdx.y * 64;
  const int nt = ntl * 64;
  const int r0 = threadIdx.x >> 4;
  const int c0 = (threadIdx.x & 15) * 4;
#pragma unroll
  for (int i = 0; i < 4; ++i) {
    int r = r0 + i * 16;
    float4 v = *(const float4*)(src + (kt + r) * srcCols + nt + c0);
    t[r][c0 + 0] = v.x; t[r][c0 + 1] = v.y; t[r][c0 + 2] = v.z; t[r][c0 + 3] = v.w;
  }
  __syncthreads();
#pragma unroll
  for (int i = 0; i < 4; ++i) {
    int r = r0 + i * 16;
    bf16x4 b = {(bf16)(t[c0 + 0][r] * scale), (bf16)(t[c0 + 1][r] * scale),
                (bf16)(t[c0 + 2][r] * scale), (bf16)(t[c0 + 3][r] * scale)};
    *(bf16x4*)(WT + (dstRow + nt + r) * 2048 + kt + c0) = b;
  }
}

// ---------------------------------------------------------------------------
// 128x128-tile bf16 GEMM, BK=64, 4 waves, double-buffered LDS (2x32KB),
// XOR slot-swizzle (slot ^= row&7, inverse-swizzled global source), counted
// vmcnt(8) pipeline (never 0 mid-loop). XCD-aware chunked block swizzle.
// ---------------------------------------------------------------------------
template <int MODE>
__global__ __launch_bounds__(256, 2) void gemm_bt(
    const bf16* __restrict__ A, const bf16* __restrict__ BT, int K, int NX,
    bf16* __restrict__ Qb, bf16* __restrict__ Kb, bf16* __restrict__ Vt,
    float* __restrict__ Cf) {
  __shared__ __align__(16) bf16 As[2][128 * 64];  // 16KB each
  __shared__ __align__(16) bf16 Bs[2][128 * 64];  // 16KB each
  const int tid = threadIdx.x;
  const int w = tid >> 6, lane = tid & 63, g = lane >> 4, lq = lane & 15;
  const int wr = w >> 1, wc = w & 1;
  const int chunk = gridDim.x >> 3;
  const int swz = (blockIdx.x & 7) * chunk + (blockIdx.x >> 3);
  const int mBase = (swz / NX) * 128, nBase = (swz % NX) * 128;
  const int sx = lq & 7;  // read-side slot XOR (frag rows are == lq mod 8)

  // stage tile kt into buffer buf: 8 per-wave VMEM ops (4 A + 4 B)
  auto STAGE = [&](int kt, int buf) {
#pragma unroll
    for (int r = 0; r < 4; ++r) {
      int c = r * 256 + tid;
      int row = c >> 3, sc = (c & 7) ^ (row & 7);
      async16(A + (mBase + row) * K + kt * 64 + sc * 8,
              &As[buf][(r * 256 + w * 64) * 8]);
      async16(BT + (nBase + row) * K + kt * 64 + sc * 8,
              &Bs[buf][(r * 256 + w * 64) * 8]);
    }
  };

  f32x4 acc[4][4] = {};
  const int KT = K >> 6;

  // prologue: tiles 0 and 1 in flight; retire tile 0
  STAGE(0, 0);
  STAGE(1, 1);
  asm volatile("s_waitcnt vmcnt(8)" ::: "memory");
  __builtin_amdgcn_s_barrier();
  __builtin_amdgcn_sched_barrier(0);

  for (int kt = 0; kt < KT; ++kt) {
    const int cur = kt & 1;
    // ---- compute tile kt from buf[cur] ----
#pragma unroll
    for (int kk = 0; kk < 2; ++kk) {
      bf16x8 af[4], bfr[4];
#pragma unroll
      for (int i = 0; i < 4; ++i)
        af[i] = *(const bf16x8*)((const char*)&As[cur][0] +
                                 (wr * 64 + i * 16 + lq) * 128 +
                                 ((((kk << 2) | g) ^ sx) << 4));
#pragma unroll
      for (int i = 0; i < 4; ++i)
        bfr[i] = *(const bf16x8*)((const char*)&Bs[cur][0] +
                                  (wc * 64 + i * 16 + lq) * 128 +
                                  ((((kk << 2) | g) ^ sx) << 4));
#pragma unroll
      for (int mi = 0; mi < 4; ++mi)
#pragma unroll
        for (int ni = 0; ni < 4; ++ni)
          acc[mi][ni] = MFMA16(af[mi], bfr[ni], acc[mi][ni]);
    }
    __builtin_amdgcn_sched_barrier(0);
    __builtin_amdgcn_s_barrier();  // all waves done reading buf[cur]
    // (every ds_read above fed an MFMA, so lgkmcnt is drained by use)

    if (kt + 2 < KT) {
      STAGE(kt + 2, cur);  // overwrite just-consumed buffer
      // retire tile kt+1 (8 per-wave loads); kt+2's 8 stay in flight
      asm volatile("s_waitcnt vmcnt(8)" ::: "memory");
      __builtin_amdgcn_s_barrier();  // tile kt+1 fully visible
    } else if (kt + 1 < KT) {
      asm volatile("s_waitcnt vmcnt(0)" ::: "memory");  // retire last tile
      __builtin_amdgcn_s_barrier();
    }
    __builtin_amdgcn_sched_barrier(0);
  }

#pragma unroll
  for (int mi = 0; mi < 4; ++mi)
#pragma unroll
    for (int ni = 0; ni < 4; ++ni) {
      const int n = nBase + wc * 64 + ni * 16 + lq;
      const int m0 = mBase + wr * 64 + mi * 16 + 4 * g;
      if (MODE == 0) {
        if (nBase < 2048) {
#pragma unroll
          for (int jr = 0; jr < 4; ++jr)
            Qb[(m0 + jr) * 2048 + n] = (bf16)acc[mi][ni][jr];
        } else if (nBase < 2560) {
#pragma unroll
          for (int jr = 0; jr < 4; ++jr)
            Kb[(m0 + jr) * 512 + (n - 2048)] = (bf16)acc[mi][ni][jr];
        } else {
          bf16x4 v = {(bf16)acc[mi][ni][0], (bf16)acc[mi][ni][1],
                      (bf16)acc[mi][ni][2], (bf16)acc[mi][ni][3]};
          *(bf16x4*)(Vt + (n - 2560) * 4096 + m0) = v;
        }
      } else {
#pragma unroll
        for (int jr = 0; jr < 4; ++jr)
          Cf[(m0 + jr) * 2048 + n] = acc[mi][ni][jr];
      }
    }
}

// ---------------------------------------------------------------------------
// Causal flash attention, swapped-QK^T on 32x32x16 MFMA, P in registers,
// software-pipelined, V single-buffered (48KB LDS) -- EXACT r8/r12 body.
// ---------------------------------------------------------------------------
__global__ __launch_bounds__(256, 2) void attn_fwd(
    const bf16* __restrict__ Qb,  // [4096][2048], scale folded
    const bf16* __restrict__ Kb,  // [4096][512]
    const bf16* __restrict__ Vt,  // [512][4096]
    bf16* __restrict__ AO) {      // [4096][2048]
  // K: [buf][64 key][128 d] 256B rows; V: [128 d][64 key] 128B rows (single).
  // Both XOR-swizzled: 16B-unit ^= (row&7), inverse applied at global source.
  __shared__ __align__(16) bf16 Ks[2][64 * 128];  // 16KB each
  __shared__ __align__(16) bf16 Vs[128 * 64];     // 16KB

  const int bid = blockIdx.x;
  const int h = bid & 15;
  const int qt = (bid < 256) ? (bid >> 4) : (31 - ((bid - 256) >> 4));
  const int kv = h >> 2;
  const int tid = threadIdx.x;
  const int w = tid >> 6, lane = tid & 63, l5 = lane & 31, g2 = lane >> 5;
  const int sxr = (l5 & 7) << 4;
  const int qbase = qt * 128;
  const int nk = 2 * (qt + 1);
  const int qw = qbase + w * 32 + l5;  // this lane's q row

  // Q fragments (B-operand): Q[qw][d = kk*16 + 8*g2 + e]
  bf16x8 aq[8];
  {
    const bf16* qrow = Qb + qw * 2048 + h * 128;
#pragma unroll
    for (int kk = 0; kk < 8; ++kk)
      aq[kk] = *(const bf16x8*)(qrow + kk * 16 + g2 * 8);
  }

  float mst = -1e30f, lst = 0.f;
  f32x16 o[4] = {};  // O^T: o[dt][r] = O^T[d = dt*32 + crow(r,g2)][q = l5]

  auto STAGE_K = [&](int t, int buf) {
#pragma unroll
    for (int r = 0; r < 4; ++r) {
      int gid = r * 256 + tid;
      int krow = gid >> 4, cu = gid & 15;
      async16(Kb + (t * 64 + krow) * 512 + kv * 128 + ((cu ^ (krow & 7)) * 8),
              &Ks[buf][(r * 256 + w * 64) * 8]);
    }
  };
  auto STAGE_V = [&](int t) {
#pragma unroll
    for (int r = 0; r < 4; ++r) {
      int gid = r * 256 + tid;
      int vrow = gid >> 3, gv = gid & 7;
      async16(Vt + (kv * 128 + vrow) * 4096 + t * 64 + ((gv ^ (vrow & 7)) * 8),
              &Vs[(r * 256 + w * 64) * 8]);
    }
  };

  // ---- prologue: K(0), V(0), K(1) in flight; compute QK(0) ----
  STAGE_K(0, 0);
  STAGE_V(0);
  STAGE_K(1, 1);
  asm volatile("s_waitcnt vmcnt(8)" ::: "memory");  // K(0) done
  __builtin_amdgcn_s_barrier();
  __builtin_amdgcn_sched_barrier(0);

  f32x16 s0 = {}, s1 = {};
  {
    const char* kb0 = (const char*)&Ks[0][0] + l5 * 256;
    __builtin_amdgcn_s_setprio(1);
#pragma unroll
    for (int kk = 0; kk < 8; ++kk) {
      const int off = (kk * 32 + g2 * 16) ^ sxr;
      bf16x8 k0 = *(const bf16x8*)(kb0 + off);
      bf16x8 k1 = *(const bf16x8*)(kb0 + 8192 + off);
      s0 = MFMA32(k0, aq[kk], s0);
      s1 = MFMA32(k1, aq[kk], s1);
    }
    __builtin_amdgcn_s_setprio(0);
  }
  __builtin_amdgcn_sched_barrier(0);
  __builtin_amdgcn_s_barrier();  // QK(0) reads done before K(2)->Ks[0]

  for (int t = 0; t < nk; ++t) {
    const int cur = t & 1, nxt = (t + 1) & 1;

    // ---- stage K(t+2) -> Ks[cur] early (K(t) reads finished last iter) ----
    STAGE_K(min(t + 2, nk - 1), cur);

    // ---- causal mask on s(t) (last two 64-key tiles only) ----
    if (t >= 2 * qt) {
      const int kb = t * 64 + 4 * g2;
#pragma unroll
      for (int r = 0; r < 16; ++r) {
        const int key = kb + (r & 3) + 8 * (r >> 2);
        if (key > qw) s0[r] = -1e30f;
        if (key + 32 > qw) s1[r] = -1e30f;
      }
    }

    // ---- online softmax(t) (exp2 domain), tree reductions ----
    {
      float mx[16];
#pragma unroll
      for (int r = 0; r < 16; ++r) mx[r] = fmaxf(s0[r], s1[r]);
#pragma unroll
      for (int off = 8; off > 0; off >>= 1)
#pragma unroll
        for (int r = 0; r < off; ++r) mx[r] = fmaxf(mx[r], mx[r + off]);
      const float pm = fmaxf(mx[0], __shfl_xor(mx[0], 32));  // cross-half max

      if (__any(pm > mst + 8.f)) {  // defer-max (T13), THR=8 in log2
        const float mn = fmaxf(mst, pm);
        const float al = exp2v(mst - mn);
        mst = mn;
        lst *= al;
#pragma unroll
        for (int dt = 0; dt < 4; ++dt)
#pragma unroll
          for (int r = 0; r < 16; ++r) o[dt][r] *= al;
      }
#pragma unroll
      for (int r = 0; r < 16; ++r) {
        s0[r] = exp2v(s0[r] - mst);
        s1[r] = exp2v(s1[r] - mst);
      }
      float sm[16];
#pragma unroll
      for (int r = 0; r < 16; ++r) sm[r] = s0[r] + s1[r];
#pragma unroll
      for (int off = 8; off > 0; off >>= 1)
#pragma unroll
        for (int r = 0; r < off; ++r) sm[r] += sm[r + off];
      lst += sm[0] + __shfl_xor(sm[0], 32);  // cross-half sum
    }

    // ---- pack P(t) to bf16 B-fragments (cvt_pk + permlane32_swap) ----
    bf16x8 pb[4];
    {
      unsigned pw0[8], pw1[8];
#pragma unroll
      for (int wi = 0; wi < 8; ++wi) {
        pw0[wi] = cvtpk(s0[2 * wi], s0[2 * wi + 1]);
        pw1[wi] = cvtpk(s1[2 * wi], s1[2 * wi + 1]);
      }
      pb[0] = mkfrag(pw0[0], pw0[1], pw0[2], pw0[3]);
      pb[1] = mkfrag(pw0[4], pw0[5], pw0[6], pw0[7]);
      pb[2] = mkfrag(pw1[0], pw1[1], pw1[2], pw1[3]);
      pb[3] = mkfrag(pw1[4], pw1[5], pw1[6], pw1[7]);
    }

    // retires K(t+1) and V(t); leaves K(t+2)'s 4 loads in flight
    asm volatile("s_waitcnt vmcnt(4)" ::: "memory");
    __builtin_amdgcn_s_barrier();
    __builtin_amdgcn_sched_barrier(0);

    // ---- MFMA cluster: QK(t+1) || PV(t), interleaved 1:1 ----
    f32x16 n0 = {}, n1 = {};
    const char* kb0 = (const char*)&Ks[nxt][0] + l5 * 256;
    const char* vb0 = (const char*)&Vs[0];
    if (t + 1 < nk) {
      __builtin_amdgcn_s_setprio(1);
#pragma unroll
      for (int i = 0; i < 8; ++i) {
        const int koff = (i * 32 + g2 * 16) ^ sxr;
        bf16x8 k0 = *(const bf16x8*)(kb0 + koff);
        bf16x8 k1 = *(const bf16x8*)(kb0 + 8192 + koff);
        n0 = MFMA32(k0, aq[i], n0);
        n1 = MFMA32(k1, aq[i], n1);
        // PV steps j = 2i, 2i+1: dt = j&3, KK = j>>2
        {
          const int j = 2 * i, dt = j & 3, KK = j >> 2;
          bf16x8 av = *(const bf16x8*)(vb0 + (dt * 32 + l5) * 128 +
                                       ((KK * 32 + g2 * 16) ^ sxr));
          o[dt] = MFMA32(av, pb[KK], o[dt]);
        }
        {
          const int j = 2 * i + 1, dt = j & 3, KK = j >> 2;
          bf16x8 av = *(const bf16x8*)(vb0 + (dt * 32 + l5) * 128 +
                                       ((KK * 32 + g2 * 16) ^ sxr));
          o[dt] = MFMA32(av, pb[KK], o[dt]);
        }
      }
      __builtin_amdgcn_s_setprio(0);
    } else {
      // tail: PV(t) only
      __builtin_amdgcn_s_setprio(1);
#pragma unroll
      for (int j = 0; j < 16; ++j) {
        const int dt = j & 3, KK = j >> 2;
        bf16x8 av = *(const bf16x8*)(vb0 + (dt * 32 + l5) * 128 +
                                     ((KK * 32 + g2 * 16) ^ sxr));
        o[dt] = MFMA32(av, pb[KK], o[dt]);
      }
      __builtin_amdgcn_s_setprio(0);
    }
    __builtin_amdgcn_sched_barrier(0);
    __builtin_amdgcn_s_barrier();  // Vs and Ks[nxt] reads done

    // ---- stage V(t+1) into the single V buffer (post-barrier: safe) ----
    if (t + 1 < nk) STAGE_V(t + 1);

    s0 = n0;
    s1 = n1;
  }

  // ---- epilogue: normalize, store (4 consecutive d per reg quad) ----
  {
    const float inv = 1.f / lst;
    bf16* aob = AO + qw * 2048 + h * 128;
#pragma unroll
    for (int dt = 0; dt < 4; ++dt)
#pragma unroll
      for (int m = 0; m < 4; ++m) {
        bf16x4 ov = {(bf16)(o[dt][4 * m + 0] * inv), (bf16)(o[dt][4 * m + 1] * inv),
                     (bf16)(o[dt][4 * m + 2] * inv), (bf16)(o[dt][4 * m + 3] * inv)};
        *(bf16x4*)(aob + dt * 32 + 8 * m + 4 * g2) = ov;
      }
  }
}

// ---------------------------------------------------------------------------
// Launch. Workspace layout (peak 54.6MB, sequential reuse):
//   [0        , 16777216) : Xb  -> reused as AO after QKV GEMM
//   [16777216 , 29360128) : WT  (Wq|Wk|Wv)^T -> reused as Wo^T
//   [29360128 , 46137344) : Qb  [4096][2048] (pre-scaled by log2e/sqrt(128))
//   [46137344 , 50331648) : Kb  [4096][512]
//   [50331648 , 54525952) : Vt  [512][4096]
// ---------------------------------------------------------------------------
extern "C" void kernel_launch(void* const* d_in, const int* in_sizes, int n_in,
                              void* d_out, int out_size, void* d_ws, size_t ws_size,
                              hipStream_t stream) {
  const float* X = (const float*)d_in[0];
  const float* Wq = (const float*)d_in[2];
  const float* Wk = (const float*)d_in[3];
  const float* Wv = (const float*)d_in[4];
  const float* Wo = (const float*)d_in[5];
  float* out = (float*)d_out;
  char* ws = (char*)d_ws;

  bf16* Xb = (bf16*)ws;
  bf16* WT = (bf16*)(ws + 16777216);
  bf16* Qb = (bf16*)(ws + 29360128);
  bf16* Kb = (bf16*)(ws + 46137344);
  bf16* Vt = (bf16*)(ws + 50331648);

  cast_bf16_kernel<<<2048, 256, 0, stream>>>(X, Xb, (4096 * 2048) / 4);
  transpose_qkv_kernel<<<dim3(48, 32), 256, 0, stream>>>(Wq, Wk, Wv, WT);

  // QKV GEMM: 32 M-tiles x 24 N-tiles = 768 blocks (768 % 8 == 0)
  gemm_bt<0><<<768, 256, 0, stream>>>(Xb, WT, 2048, 24, Qb, Kb, Vt, (float*)nullptr);

  transpose_cast_kernel<<<dim3(32, 32), 256, 0, stream>>>(Wo, 2048, WT, 1.0f);

  attn_fwd<<<512, 256, 0, stream>>>(Qb, Kb, Vt, Xb);

  // O GEMM: 32 M-tiles x 16 N-tiles = 512 blocks (512 % 8 == 0)
  gemm_bt<1><<<512, 256, 0, stream>>>(Xb, WT, 2048, 16, (bf16*)nullptr,
                                      (bf16*)nullptr, (bf16*)nullptr, out);
}

// Round 15
// 230.919 us; speedup vs baseline: 1.0738x; 1.0738x over previous
//
#include <hip/hip_runtime.h>

// ---------------------------------------------------------------------------
// Fused GQA attention block for MI355X (gfx950), bf16 MFMA pipeline.
// B=1, S=4096, H=2048, NH=16, NKV=4, HD=128, GROUPS=4, causal mask hardcoded.
// Round 15: revert to the r13 configuration (best measured: 231.3us).
// r14's counted-vmcnt double-buffer GEMM regressed (+17us): the vmcnt(0)
// drain was already hidden by 2-blocks/CU wave overlap, and the extra
// barrier + sched_barrier fences cost ~20% (m99/m131/m141-class result).
// GEMM: single-buffer BK=64, XOR slot-swizzle (conflict-free ds_read_b128).
// Attention: frozen r8/r12 body (130.5us, knife-edge VGPR=128).
// ---------------------------------------------------------------------------

typedef __bf16 bf16;
typedef float f32x4 __attribute__((ext_vector_type(4)));
typedef float f32x16 __attribute__((ext_vector_type(16)));
typedef bf16 bf16x4 __attribute__((ext_vector_type(4)));
typedef bf16 bf16x8 __attribute__((ext_vector_type(8)));
typedef unsigned u32x4 __attribute__((ext_vector_type(4)));

#define MFMA16(A, B, C) __builtin_amdgcn_mfma_f32_16x16x32_bf16((A), (B), (C), 0, 0, 0)
#define MFMA32(A, B, C) __builtin_amdgcn_mfma_f32_32x32x16_bf16((A), (B), (C), 0, 0, 0)

__device__ __forceinline__ void async16(const bf16* g, bf16* l) {
  __builtin_amdgcn_global_load_lds(
      (const __attribute__((address_space(1))) unsigned int*)g,
      (__attribute__((address_space(3))) unsigned int*)l, 16, 0, 0);
}

__device__ __forceinline__ float exp2v(float x) {
  float r; asm("v_exp_f32 %0, %1" : "=v"(r) : "v"(x)); return r;
}
__device__ __forceinline__ unsigned cvtpk(float a, float b) {  // lo=a, hi=b
  unsigned r; asm("v_cvt_pk_bf16_f32 %0, %1, %2" : "=v"(r) : "v"(a), "v"(b)); return r;
}
// v_permlane32_swap_b32: a' = [a_lo|b_lo], b' = [a_hi|b_hi].
// ONLY safe when a and b are distinct SSA values (else RA may coalesce regs).
#define PLSWAP(a, b) asm("v_permlane32_swap_b32 %0, %1" : "+v"(a), "+v"(b))

// B-fragment builder: dwords {a0', a1', c0', c1'} after half-swaps
__device__ __forceinline__ bf16x8 mkfrag(unsigned a0, unsigned a1,
                                         unsigned c0, unsigned c1) {
  PLSWAP(a0, c0);
  PLSWAP(a1, c1);
  u32x4 t = {a0, a1, c0, c1};
  return __builtin_bit_cast(bf16x8, t);
}

// ---------------------------------------------------------------------------
// f32 -> bf16 elementwise cast
// ---------------------------------------------------------------------------
__global__ void cast_bf16_kernel(const float* __restrict__ in,
                                 bf16* __restrict__ out, int n4) {
  int i = blockIdx.x * blockDim.x + threadIdx.x;
  int stride = gridDim.x * blockDim.x;
  for (; i < n4; i += stride) {
    float4 v = ((const float4*)in)[i];
    bf16x4 o = {(bf16)v.x, (bf16)v.y, (bf16)v.z, (bf16)v.w};
    ((bf16x4*)out)[i] = o;
  }
}

// ---------------------------------------------------------------------------
// Transpose + cast: src f32 [2048][srcCols] -> dst bf16 [srcCols][2048], *scale
// ---------------------------------------------------------------------------
__global__ void transpose_cast_kernel(const float* __restrict__ src, int srcCols,
                                      bf16* __restrict__ dst, float scale) {
  __shared__ float t[64][65];
  const int kt = blockIdx.y * 64;
  const int nt = blockIdx.x * 64;
  const int r0 = threadIdx.x >> 4;
  const int c0 = (threadIdx.x & 15) * 4;
#pragma unroll
  for (int i = 0; i < 4; ++i) {
    int r = r0 + i * 16;
    float4 v = *(const float4*)(src + (kt + r) * srcCols + nt + c0);
    t[r][c0 + 0] = v.x; t[r][c0 + 1] = v.y; t[r][c0 + 2] = v.z; t[r][c0 + 3] = v.w;
  }
  __syncthreads();
#pragma unroll
  for (int i = 0; i < 4; ++i) {
    int r = r0 + i * 16;
    bf16x4 b = {(bf16)(t[c0 + 0][r] * scale), (bf16)(t[c0 + 1][r] * scale),
                (bf16)(t[c0 + 2][r] * scale), (bf16)(t[c0 + 3][r] * scale)};
    *(bf16x4*)(dst + (nt + r) * 2048 + kt + c0) = b;
  }
}

// ---------------------------------------------------------------------------
// Merged Wq/Wk/Wv transpose+cast into WT (one launch instead of three).
// blockIdx.x: 0..31 -> Wq (32 col-tiles), 32..39 -> Wk, 40..47 -> Wv.
// ---------------------------------------------------------------------------
__global__ void transpose_qkv_kernel(const float* __restrict__ Wq,
                                     const float* __restrict__ Wk,
                                     const float* __restrict__ Wv,
                                     bf16* __restrict__ WT) {
  __shared__ float t[64][65];
  const int bx = blockIdx.x;
  const float* src;
  int srcCols, ntl, dstRow;
  float scale;
  if (bx < 32) {
    src = Wq; srcCols = 2048; ntl = bx; dstRow = 0;
    scale = 0.08838834764831845f * 1.4426950408889634f;  // 1/sqrt(128) * log2e
  } else if (bx < 40) {
    src = Wk; srcCols = 512; ntl = bx - 32; dstRow = 2048; scale = 1.0f;
  } else {
    src = Wv; srcCols = 512; ntl = bx - 40; dstRow = 2560; scale = 1.0f;
  }
  const int kt = blockIdx.y * 64;
  const int nt = ntl * 64;
  const int r0 = threadIdx.x >> 4;
  const int c0 = (threadIdx.x & 15) * 4;
#pragma unroll
  for (int i = 0; i < 4; ++i) {
    int r = r0 + i * 16;
    float4 v = *(const float4*)(src + (kt + r) * srcCols + nt + c0);
    t[r][c0 + 0] = v.x; t[r][c0 + 1] = v.y; t[r][c0 + 2] = v.z; t[r][c0 + 3] = v.w;
  }
  __syncthreads();
#pragma unroll
  for (int i = 0; i < 4; ++i) {
    int r = r0 + i * 16;
    bf16x4 b = {(bf16)(t[c0 + 0][r] * scale), (bf16)(t[c0 + 1][r] * scale),
                (bf16)(t[c0 + 2][r] * scale), (bf16)(t[c0 + 3][r] * scale)};
    *(bf16x4*)(WT + (dstRow + nt + r) * 2048 + kt + c0) = b;
  }
}

// ---------------------------------------------------------------------------
// 128x128-tile bf16 GEMM, BK=64, 4 waves, global_load_lds staging, XOR-swizzled
// LDS ([128][64] bf16 = 128B rows, 8 x 16B slots; slot ^= row&7; inverse
// swizzle on the global source per rule #21). XCD-aware chunked block swizzle.
// ---------------------------------------------------------------------------
template <int MODE>
__global__ __launch_bounds__(256, 2) void gemm_bt(
    const bf16* __restrict__ A, const bf16* __restrict__ BT, int K, int NX,
    bf16* __restrict__ Qb, bf16* __restrict__ Kb, bf16* __restrict__ Vt,
    float* __restrict__ Cf) {
  __shared__ __align__(16) bf16 As[128 * 64];  // 16KB
  __shared__ __align__(16) bf16 Bs[128 * 64];  // 16KB
  const int tid = threadIdx.x;
  const int w = tid >> 6, lane = tid & 63, g = lane >> 4, lq = lane & 15;
  const int wr = w >> 1, wc = w & 1;
  const int chunk = gridDim.x >> 3;
  const int swz = (blockIdx.x & 7) * chunk + (blockIdx.x >> 3);
  const int mBase = (swz / NX) * 128, nBase = (swz % NX) * 128;
  const int sx = lq & 7;  // read-side slot XOR (frag rows are == lq mod 8)

  f32x4 acc[4][4] = {};
  const int KT = K >> 6;
  for (int kt = 0; kt < KT; ++kt) {
    // stage A/B tiles [128][64] (1024 x 16B chunks each, 4/thread/matrix);
    // global source column pre-swizzled so linear LDS ends up slot-swizzled
#pragma unroll
    for (int r = 0; r < 4; ++r) {
      int c = r * 256 + tid;
      int row = c >> 3, sc = (c & 7) ^ (row & 7);
      async16(A + (mBase + row) * K + kt * 64 + sc * 8, As + (r * 256 + w * 64) * 8);
      async16(BT + (nBase + row) * K + kt * 64 + sc * 8, Bs + (r * 256 + w * 64) * 8);
    }
    asm volatile("s_waitcnt vmcnt(0)" ::: "memory");
    __syncthreads();

#pragma unroll
    for (int kk = 0; kk < 2; ++kk) {
      bf16x8 af[4], bfr[4];
#pragma unroll
      for (int i = 0; i < 4; ++i)
        af[i] = *(const bf16x8*)((const char*)As + (wr * 64 + i * 16 + lq) * 128 +
                                 ((((kk << 2) | g) ^ sx) << 4));
#pragma unroll
      for (int i = 0; i < 4; ++i)
        bfr[i] = *(const bf16x8*)((const char*)Bs + (wc * 64 + i * 16 + lq) * 128 +
                                  ((((kk << 2) | g) ^ sx) << 4));
#pragma unroll
      for (int mi = 0; mi < 4; ++mi)
#pragma unroll
        for (int ni = 0; ni < 4; ++ni)
          acc[mi][ni] = MFMA16(af[mi], bfr[ni], acc[mi][ni]);
    }
    __syncthreads();
  }

#pragma unroll
  for (int mi = 0; mi < 4; ++mi)
#pragma unroll
    for (int ni = 0; ni < 4; ++ni) {
      const int n = nBase + wc * 64 + ni * 16 + lq;
      const int m0 = mBase + wr * 64 + mi * 16 + 4 * g;
      if (MODE == 0) {
        if (nBase < 2048) {
#pragma unroll
          for (int jr = 0; jr < 4; ++jr)
            Qb[(m0 + jr) * 2048 + n] = (bf16)acc[mi][ni][jr];
        } else if (nBase < 2560) {
#pragma unroll
          for (int jr = 0; jr < 4; ++jr)
            Kb[(m0 + jr) * 512 + (n - 2048)] = (bf16)acc[mi][ni][jr];
        } else {
          bf16x4 v = {(bf16)acc[mi][ni][0], (bf16)acc[mi][ni][1],
                      (bf16)acc[mi][ni][2], (bf16)acc[mi][ni][3]};
          *(bf16x4*)(Vt + (n - 2560) * 4096 + m0) = v;
        }
      } else {
#pragma unroll
        for (int jr = 0; jr < 4; ++jr)
          Cf[(m0 + jr) * 2048 + n] = acc[mi][ni][jr];
      }
    }
}

// ---------------------------------------------------------------------------
// Causal flash attention, swapped-QK^T on 32x32x16 MFMA, P in registers,
// software-pipelined, V single-buffered (48KB LDS) -- EXACT r8/r12 body.
// ---------------------------------------------------------------------------
__global__ __launch_bounds__(256, 2) void attn_fwd(
    const bf16* __restrict__ Qb,  // [4096][2048], scale folded
    const bf16* __restrict__ Kb,  // [4096][512]
    const bf16* __restrict__ Vt,  // [512][4096]
    bf16* __restrict__ AO) {      // [4096][2048]
  // K: [buf][64 key][128 d] 256B rows; V: [128 d][64 key] 128B rows (single).
  // Both XOR-swizzled: 16B-unit ^= (row&7), inverse applied at global source.
  __shared__ __align__(16) bf16 Ks[2][64 * 128];  // 16KB each
  __shared__ __align__(16) bf16 Vs[128 * 64];     // 16KB

  const int bid = blockIdx.x;
  const int h = bid & 15;
  const int qt = (bid < 256) ? (bid >> 4) : (31 - ((bid - 256) >> 4));
  const int kv = h >> 2;
  const int tid = threadIdx.x;
  const int w = tid >> 6, lane = tid & 63, l5 = lane & 31, g2 = lane >> 5;
  const int sxr = (l5 & 7) << 4;
  const int qbase = qt * 128;
  const int nk = 2 * (qt + 1);
  const int qw = qbase + w * 32 + l5;  // this lane's q row

  // Q fragments (B-operand): Q[qw][d = kk*16 + 8*g2 + e]
  bf16x8 aq[8];
  {
    const bf16* qrow = Qb + qw * 2048 + h * 128;
#pragma unroll
    for (int kk = 0; kk < 8; ++kk)
      aq[kk] = *(const bf16x8*)(qrow + kk * 16 + g2 * 8);
  }

  float mst = -1e30f, lst = 0.f;
  f32x16 o[4] = {};  // O^T: o[dt][r] = O^T[d = dt*32 + crow(r,g2)][q = l5]

  auto STAGE_K = [&](int t, int buf) {
#pragma unroll
    for (int r = 0; r < 4; ++r) {
      int gid = r * 256 + tid;
      int krow = gid >> 4, cu = gid & 15;
      async16(Kb + (t * 64 + krow) * 512 + kv * 128 + ((cu ^ (krow & 7)) * 8),
              &Ks[buf][(r * 256 + w * 64) * 8]);
    }
  };
  auto STAGE_V = [&](int t) {
#pragma unroll
    for (int r = 0; r < 4; ++r) {
      int gid = r * 256 + tid;
      int vrow = gid >> 3, gv = gid & 7;
      async16(Vt + (kv * 128 + vrow) * 4096 + t * 64 + ((gv ^ (vrow & 7)) * 8),
              &Vs[(r * 256 + w * 64) * 8]);
    }
  };

  // ---- prologue: K(0), V(0), K(1) in flight; compute QK(0) ----
  STAGE_K(0, 0);
  STAGE_V(0);
  STAGE_K(1, 1);
  asm volatile("s_waitcnt vmcnt(8)" ::: "memory");  // K(0) done
  __builtin_amdgcn_s_barrier();
  __builtin_amdgcn_sched_barrier(0);

  f32x16 s0 = {}, s1 = {};
  {
    const char* kb0 = (const char*)&Ks[0][0] + l5 * 256;
    __builtin_amdgcn_s_setprio(1);
#pragma unroll
    for (int kk = 0; kk < 8; ++kk) {
      const int off = (kk * 32 + g2 * 16) ^ sxr;
      bf16x8 k0 = *(const bf16x8*)(kb0 + off);
      bf16x8 k1 = *(const bf16x8*)(kb0 + 8192 + off);
      s0 = MFMA32(k0, aq[kk], s0);
      s1 = MFMA32(k1, aq[kk], s1);
    }
    __builtin_amdgcn_s_setprio(0);
  }
  __builtin_amdgcn_sched_barrier(0);
  __builtin_amdgcn_s_barrier();  // QK(0) reads done before K(2)->Ks[0]

  for (int t = 0; t < nk; ++t) {
    const int cur = t & 1, nxt = (t + 1) & 1;

    // ---- stage K(t+2) -> Ks[cur] early (K(t) reads finished last iter) ----
    STAGE_K(min(t + 2, nk - 1), cur);

    // ---- causal mask on s(t) (last two 64-key tiles only) ----
    if (t >= 2 * qt) {
      const int kb = t * 64 + 4 * g2;
#pragma unroll
      for (int r = 0; r < 16; ++r) {
        const int key = kb + (r & 3) + 8 * (r >> 2);
        if (key > qw) s0[r] = -1e30f;
        if (key + 32 > qw) s1[r] = -1e30f;
      }
    }

    // ---- online softmax(t) (exp2 domain), tree reductions ----
    {
      float mx[16];
#pragma unroll
      for (int r = 0; r < 16; ++r) mx[r] = fmaxf(s0[r], s1[r]);
#pragma unroll
      for (int off = 8; off > 0; off >>= 1)
#pragma unroll
        for (int r = 0; r < off; ++r) mx[r] = fmaxf(mx[r], mx[r + off]);
      const float pm = fmaxf(mx[0], __shfl_xor(mx[0], 32));  // cross-half max

      if (__any(pm > mst + 8.f)) {  // defer-max (T13), THR=8 in log2
        const float mn = fmaxf(mst, pm);
        const float al = exp2v(mst - mn);
        mst = mn;
        lst *= al;
#pragma unroll
        for (int dt = 0; dt < 4; ++dt)
#pragma unroll
          for (int r = 0; r < 16; ++r) o[dt][r] *= al;
      }
#pragma unroll
      for (int r = 0; r < 16; ++r) {
        s0[r] = exp2v(s0[r] - mst);
        s1[r] = exp2v(s1[r] - mst);
      }
      float sm[16];
#pragma unroll
      for (int r = 0; r < 16; ++r) sm[r] = s0[r] + s1[r];
#pragma unroll
      for (int off = 8; off > 0; off >>= 1)
#pragma unroll
        for (int r = 0; r < off; ++r) sm[r] += sm[r + off];
      lst += sm[0] + __shfl_xor(sm[0], 32);  // cross-half sum
    }

    // ---- pack P(t) to bf16 B-fragments (cvt_pk + permlane32_swap) ----
    bf16x8 pb[4];
    {
      unsigned pw0[8], pw1[8];
#pragma unroll
      for (int wi = 0; wi < 8; ++wi) {
        pw0[wi] = cvtpk(s0[2 * wi], s0[2 * wi + 1]);
        pw1[wi] = cvtpk(s1[2 * wi], s1[2 * wi + 1]);
      }
      pb[0] = mkfrag(pw0[0], pw0[1], pw0[2], pw0[3]);
      pb[1] = mkfrag(pw0[4], pw0[5], pw0[6], pw0[7]);
      pb[2] = mkfrag(pw1[0], pw1[1], pw1[2], pw1[3]);
      pb[3] = mkfrag(pw1[4], pw1[5], pw1[6], pw1[7]);
    }

    // retires K(t+1) and V(t); leaves K(t+2)'s 4 loads in flight
    asm volatile("s_waitcnt vmcnt(4)" ::: "memory");
    __builtin_amdgcn_s_barrier();
    __builtin_amdgcn_sched_barrier(0);

    // ---- MFMA cluster: QK(t+1) || PV(t), interleaved 1:1 ----
    f32x16 n0 = {}, n1 = {};
    const char* kb0 = (const char*)&Ks[nxt][0] + l5 * 256;
    const char* vb0 = (const char*)&Vs[0];
    if (t + 1 < nk) {
      __builtin_amdgcn_s_setprio(1);
#pragma unroll
      for (int i = 0; i < 8; ++i) {
        const int koff = (i * 32 + g2 * 16) ^ sxr;
        bf16x8 k0 = *(const bf16x8*)(kb0 + koff);
        bf16x8 k1 = *(const bf16x8*)(kb0 + 8192 + koff);
        n0 = MFMA32(k0, aq[i], n0);
        n1 = MFMA32(k1, aq[i], n1);
        // PV steps j = 2i, 2i+1: dt = j&3, KK = j>>2
        {
          const int j = 2 * i, dt = j & 3, KK = j >> 2;
          bf16x8 av = *(const bf16x8*)(vb0 + (dt * 32 + l5) * 128 +
                                       ((KK * 32 + g2 * 16) ^ sxr));
          o[dt] = MFMA32(av, pb[KK], o[dt]);
        }
        {
          const int j = 2 * i + 1, dt = j & 3, KK = j >> 2;
          bf16x8 av = *(const bf16x8*)(vb0 + (dt * 32 + l5) * 128 +
                                       ((KK * 32 + g2 * 16) ^ sxr));
          o[dt] = MFMA32(av, pb[KK], o[dt]);
        }
      }
      __builtin_amdgcn_s_setprio(0);
    } else {
      // tail: PV(t) only
      __builtin_amdgcn_s_setprio(1);
#pragma unroll
      for (int j = 0; j < 16; ++j) {
        const int dt = j & 3, KK = j >> 2;
        bf16x8 av = *(const bf16x8*)(vb0 + (dt * 32 + l5) * 128 +
                                     ((KK * 32 + g2 * 16) ^ sxr));
        o[dt] = MFMA32(av, pb[KK], o[dt]);
      }
      __builtin_amdgcn_s_setprio(0);
    }
    __builtin_amdgcn_sched_barrier(0);
    __builtin_amdgcn_s_barrier();  // Vs and Ks[nxt] reads done

    // ---- stage V(t+1) into the single V buffer (post-barrier: safe) ----
    if (t + 1 < nk) STAGE_V(t + 1);

    s0 = n0;
    s1 = n1;
  }

  // ---- epilogue: normalize, store (4 consecutive d per reg quad) ----
  {
    const float inv = 1.f / lst;
    bf16* aob = AO + qw * 2048 + h * 128;
#pragma unroll
    for (int dt = 0; dt < 4; ++dt)
#pragma unroll
      for (int m = 0; m < 4; ++m) {
        bf16x4 ov = {(bf16)(o[dt][4 * m + 0] * inv), (bf16)(o[dt][4 * m + 1] * inv),
                     (bf16)(o[dt][4 * m + 2] * inv), (bf16)(o[dt][4 * m + 3] * inv)};
        *(bf16x4*)(aob + dt * 32 + 8 * m + 4 * g2) = ov;
      }
  }
}

// ---------------------------------------------------------------------------
// Launch. Workspace layout (peak 54.6MB, sequential reuse):
//   [0        , 16777216) : Xb  -> reused as AO after QKV GEMM
//   [16777216 , 29360128) : WT  (Wq|Wk|Wv)^T -> reused as Wo^T
//   [29360128 , 46137344) : Qb  [4096][2048] (pre-scaled by log2e/sqrt(128))
//   [46137344 , 50331648) : Kb  [4096][512]
//   [50331648 , 54525952) : Vt  [512][4096]
// ---------------------------------------------------------------------------
extern "C" void kernel_launch(void* const* d_in, const int* in_sizes, int n_in,
                              void* d_out, int out_size, void* d_ws, size_t ws_size,
                              hipStream_t stream) {
  const float* X = (const float*)d_in[0];
  const float* Wq = (const float*)d_in[2];
  const float* Wk = (const float*)d_in[3];
  const float* Wv = (const float*)d_in[4];
  const float* Wo = (const float*)d_in[5];
  float* out = (float*)d_out;
  char* ws = (char*)d_ws;

  bf16* Xb = (bf16*)ws;
  bf16* WT = (bf16*)(ws + 16777216);
  bf16* Qb = (bf16*)(ws + 29360128);
  bf16* Kb = (bf16*)(ws + 46137344);
  bf16* Vt = (bf16*)(ws + 50331648);

  cast_bf16_kernel<<<2048, 256, 0, stream>>>(X, Xb, (4096 * 2048) / 4);
  transpose_qkv_kernel<<<dim3(48, 32), 256, 0, stream>>>(Wq, Wk, Wv, WT);

  // QKV GEMM: 32 M-tiles x 24 N-tiles = 768 blocks (768 % 8 == 0)
  gemm_bt<0><<<768, 256, 0, stream>>>(Xb, WT, 2048, 24, Qb, Kb, Vt, (float*)nullptr);

  transpose_cast_kernel<<<dim3(32, 32), 256, 0, stream>>>(Wo, 2048, WT, 1.0f);

  attn_fwd<<<512, 256, 0, stream>>>(Qb, Kb, Vt, Xb);

  // O GEMM: 32 M-tiles x 16 N-tiles = 512 blocks (512 % 8 == 0)
  gemm_bt<1><<<512, 256, 0, stream>>>(Xb, WT, 2048, 16, (bf16*)nullptr,
                                      (bf16*)nullptr, (bf16*)nullptr, out);
}